// Round 8
// baseline (187.842 us; speedup 1.0000x reference)
//
#include <hip/hip_runtime.h>

#define T_SEQ   2048
#define DM      2048
#define N_Q     16
#define N_KV    4
#define HD      128
#define WIN     512
#define NB      2
#define NQKV    3072
// 1/sqrt(128) * log2(e): attention computed in exp2 domain
#define QK_SCALE_L2E 0.12751744f

typedef short bf16x8 __attribute__((ext_vector_type(8)));
typedef float f32x4  __attribute__((ext_vector_type(4)));
typedef unsigned short us4v __attribute__((ext_vector_type(4)));

__device__ __forceinline__ unsigned short f2bf(float f) {
    union { float f; unsigned u; } v; v.f = f;
    unsigned u = v.u;
    u += 0x7fffu + ((u >> 16) & 1u);           // RNE
    return (unsigned short)(u >> 16);
}
__device__ __forceinline__ float bf2f(unsigned short h) {
    union { unsigned u; float f; } v; v.u = ((unsigned)h) << 16;
    return v.f;
}
__device__ __forceinline__ unsigned cvt_pk_bf16(float a, float b) {
    unsigned r;
    asm("v_cvt_pk_bf16_f32 %0, %1, %2" : "=v"(r) : "v"(a), "v"(b));
    return r;   // low16 = bf16(a), high16 = bf16(b)
}

#define GLOAD_LDS16(g, l) __builtin_amdgcn_global_load_lds( \
    (const __attribute__((address_space(1))) void*)(g),     \
    (__attribute__((address_space(3))) void*)(l), 16, 0, 0)

struct us4 { unsigned short a, b, c, d; };

// ---------------- fused prep A: x->bf16, 4 weight transposes, rope table ----------------
// flat grid: [0,8192) x-convert | [8192,18432) transposes | [18432,18944) rope table

__global__ __launch_bounds__(256)
void prep_a(const float* __restrict__ x, const float* __restrict__ wq,
            const float* __restrict__ wk, const float* __restrict__ wv,
            const float* __restrict__ wo,
            unsigned short* __restrict__ xbf, unsigned short* __restrict__ wqkvT,
            unsigned short* __restrict__ woT,
            float* __restrict__ cosT, float* __restrict__ sinT) {
    __shared__ float tile[32][33];
    int blk = blockIdx.x;
    if (blk < 8192) {                               // x: f32 -> bf16, 4 elems/thread
        long i = ((long)blk * 256 + threadIdx.x) * 4;
        float4 f = *(const float4*)(x + i);
        us4 o; o.a = f2bf(f.x); o.b = f2bf(f.y); o.c = f2bf(f.z); o.d = f2bf(f.w);
        *(us4*)(xbf + i) = o;
        return;
    }
    blk -= 8192;
    if (blk < 10240) {                              // weight transposes
        const float* in; unsigned short* outp; int C, bx, by;
        if (blk < 4096)      { in = wq; outp = wqkvT;                         C = DM;  bx = blk & 63;          by = blk >> 6; }
        else if (blk < 5120) { int k = blk - 4096; in = wk; outp = wqkvT + (long)DM * DM;         C = 512; bx = k & 15; by = k >> 4; }
        else if (blk < 6144) { int k = blk - 5120; in = wv; outp = wqkvT + (long)(DM + 512) * DM; C = 512; bx = k & 15; by = k >> 4; }
        else                 { int k = blk - 6144; in = wo; outp = woT;                           C = DM;  bx = k & 63; by = k >> 6; }
        const int c0 = bx * 32, r0 = by * 32;
        const int tx = threadIdx.x & 31, ty = threadIdx.x >> 5;
#pragma unroll
        for (int i = 0; i < 4; ++i)
            tile[ty + i * 8][tx] = in[(long)(r0 + ty + i * 8) * C + c0 + tx];
        __syncthreads();
#pragma unroll
        for (int i = 0; i < 4; ++i)
            outp[(long)(c0 + ty + i * 8) * DM + r0 + tx] = f2bf(tile[tx][ty + i * 8]);
        return;
    }
    blk -= 10240;                                   // rope table (512 blocks)
    const int idx = blk * 256 + threadIdx.x;        // < 2048*64
    const int t = idx >> 6, d = idx & 63;
    const float inv = __expf(-(float)d * (9.210340371976184f / 64.0f)); // 10000^(-d/64)
    const float ang = (float)t * inv;
    cosT[idx] = cosf(ang);
    sinT[idx] = sinf(ang);
}

// ---------------- fused prep B: rope apply (q,k) + v transpose ----------------
// flat grid: [0,5120) rope | [5120,7168) v-transpose

__global__ __launch_bounds__(256)
void prep_b(unsigned short* __restrict__ qkv,
            const float* __restrict__ cosT, const float* __restrict__ sinT,
            unsigned short* __restrict__ vt) {
    __shared__ unsigned short stile[32][33];
    int blk = blockIdx.x;
    if (blk < 5120) {                               // RoPE, 4 d-values/thread
        const int idx = blk * 256 + threadIdx.x;    // 4096*20*16
        const int d4 = (idx & 15) * 4;
        const int hh = (idx >> 4) % 20;
        const int row = idx / (16 * 20);
        const int t = row & (T_SEQ - 1);
        const int col = (hh < N_Q) ? hh * HD + d4 : DM + (hh - N_Q) * HD + d4;
        unsigned short* p = qkv + (long)row * NQKV + col;
        us4v a = *(const us4v*)p;
        us4v b = *(const us4v*)(p + 64);
        float4 c = *(const float4*)&cosT[t * 64 + d4];
        float4 s = *(const float4*)&sinT[t * 64 + d4];
        const float sc = (hh < N_Q) ? QK_SCALE_L2E : 1.0f;
        us4v o1, o2;
        const float cc[4] = { c.x, c.y, c.z, c.w }, ss[4] = { s.x, s.y, s.z, s.w };
#pragma unroll
        for (int i = 0; i < 4; ++i) {
            const float av = bf2f(a[i]), bv = bf2f(b[i]);
            o1[i] = f2bf((av * cc[i] - bv * ss[i]) * sc);
            o2[i] = f2bf((bv * cc[i] + av * ss[i]) * sc);
        }
        *(us4v*)p        = o1;
        *(us4v*)(p + 64) = o2;
        return;
    }
    blk -= 5120;                                    // v transpose (2048 blocks)
    const int bh = blk >> 8;                        // b*4 + hkv
    const int d0 = ((blk >> 6) & 3) * 32;
    const int t0 = (blk & 63) * 32;
    const int tx = threadIdx.x & 31, ty = threadIdx.x >> 5;
    const long inbase = (long)(bh >> 2) * T_SEQ;
    const int coff = DM + N_KV * HD + (bh & 3) * HD;   // 2560 + hkv*128
#pragma unroll
    for (int i = 0; i < 4; ++i)
        stile[ty + i * 8][tx] = qkv[(inbase + t0 + ty + i * 8) * NQKV + coff + d0 + tx];
    __syncthreads();
#pragma unroll
    for (int i = 0; i < 4; ++i)
        vt[((long)bh * HD + d0 + ty + i * 8) * T_SEQ + t0 + tx] = stile[tx][ty + i * 8];
}

// ---------------- GEMM: C[M][ldc] = A[M][K] * Bt[N][K]^T  (m97 structure + XCD swizzle) ----------------

template<int OUT_BF16>
__global__ __launch_bounds__(256)
void gemm_bt(const unsigned short* __restrict__ A,
             const unsigned short* __restrict__ Bt,
             void* __restrict__ Cvoid, int K, int ldc) {
    __shared__ __align__(16) unsigned short sA[128 * 64];
    __shared__ __align__(16) unsigned short sB[128 * 64];
    const int tid = threadIdx.x;
    const int lane = tid & 63;
    const int wid = tid >> 6;
    const int wr = (wid >> 1) * 64, wc = (wid & 1) * 64;

    // XCD-aware bijective swizzle (nwg divisible by 8 in all launches)
    const int gx = gridDim.x;
    const int nwg = gx * gridDim.y;
    int flat = blockIdx.y * gx + blockIdx.x;
    flat = (flat & 7) * (nwg >> 3) + (flat >> 3);
    const long Arow0 = (long)(flat / gx) * 128;
    const long Brow0 = (long)(flat % gx) * 128;

    f32x4 acc[4][4] = {};

    for (int kt = 0; kt < K; kt += 64) {
        __syncthreads();
#pragma unroll
        for (int n = 0; n < 4; ++n) {
            const int linb = n * 256 + wid * 64;      // wave-uniform 16B-chunk base
            const int lin  = linb + lane;             // this lane's chunk
            const int row  = lin >> 3;                // 8 chunks per 64-elem row
            const int sc   = (lin & 7) ^ (row & 7);   // pre-swizzled global source
            const unsigned short* gA = A  + (Arow0 + row) * K + kt + sc * 8;
            const unsigned short* gB = Bt + (Brow0 + row) * K + kt + sc * 8;
            GLOAD_LDS16(gA, &sA[linb * 8]);
            GLOAD_LDS16(gB, &sB[linb * 8]);
        }
        __syncthreads();
#pragma unroll
        for (int kk = 0; kk < 2; ++kk) {
            bf16x8 av[4], bv[4];
#pragma unroll
            for (int i = 0; i < 4; ++i) {
                const int row = wr + i * 16 + (lane & 15);
                const int c = (kk * 4 + (lane >> 4)) ^ (row & 7);
                av[i] = *(const bf16x8*)&sA[row * 64 + c * 8];
            }
#pragma unroll
            for (int j = 0; j < 4; ++j) {
                const int row = wc + j * 16 + (lane & 15);
                const int c = (kk * 4 + (lane >> 4)) ^ (row & 7);
                bv[j] = *(const bf16x8*)&sB[row * 64 + c * 8];
            }
#pragma unroll
            for (int i = 0; i < 4; ++i)
#pragma unroll
                for (int j = 0; j < 4; ++j)
                    acc[i][j] = __builtin_amdgcn_mfma_f32_16x16x32_bf16(av[i], bv[j], acc[i][j], 0, 0, 0);
        }
    }

    const int r0 = (int)Arow0 + wr + ((lane >> 4) << 2);
    const int c0 = (int)Brow0 + wc + (lane & 15);
    if (OUT_BF16) {
        unsigned short* C = (unsigned short*)Cvoid;
#pragma unroll
        for (int i = 0; i < 4; ++i)
#pragma unroll
            for (int j = 0; j < 4; ++j)
#pragma unroll
                for (int r = 0; r < 4; ++r)
                    C[(long)(r0 + i * 16 + r) * ldc + c0 + j * 16] = f2bf(acc[i][j][r]);
    } else {
        float* C = (float*)Cvoid;
#pragma unroll
        for (int i = 0; i < 4; ++i)
#pragma unroll
            for (int j = 0; j < 4; ++j)
#pragma unroll
                for (int r = 0; r < 4; ++r)
                    C[(long)(r0 + i * 16 + r) * ldc + c0 + j * 16] = acc[i][j][r];
    }
}

// ---------------- flash attention, sliding window ----------------
// grid (T/32, N_KV, B), 256 threads = 4 waves; wave w handles q-head hkv*4+w,
// q-rows qt*32 + [0,32) (2 q-frags). 4 waves share staged K/V tiles.
// LDS 80 KB -> 2 blocks/CU. Swapped QK^T, lane-local softmax, exp2 domain,
// defer-max, double-buffered K/V staging via global_load_lds.

__global__ __launch_bounds__(256)
void attn_kernel(const unsigned short* __restrict__ qkv,
                 const unsigned short* __restrict__ vt,
                 unsigned short* __restrict__ aout) {
    const int qt = blockIdx.x, hkv = blockIdx.y, b = blockIdx.z;
    const int tid = threadIdx.x, lane = tid & 63, w = tid >> 6;
    const int qh = hkv * 4 + w;                // q-head for this wave
    const int q0w = qt * 32;                   // block's first q-row
    const int lo = lane & 15, hi = lane >> 4;

    __shared__ __align__(16) unsigned short sK[2][64 * 128];   // [key][d], chunk-swizzled (32 KB)
    __shared__ __align__(16) unsigned short sV[2][128 * 64];   // [d][key], chunk-swizzled (32 KB)
    __shared__ __align__(16) unsigned short plds[4][32 * 64];  // per-wave P (16 KB)
    unsigned short* pl = plds[w];

    // Q fragments: 2 q-frags x 4 k-chunks
    bf16x8 qf2[2][4];
#pragma unroll
    for (int f = 0; f < 2; ++f) {
        const unsigned short* qp = qkv + (long)(b * T_SEQ + q0w + f * 16 + lo) * NQKV + qh * HD + hi * 8;
#pragma unroll
        for (int s = 0; s < 4; ++s) qf2[f][s] = *(const bf16x8*)(qp + s * 32);
    }

    f32x4 of[8][2] = {};
    float m_r[2] = { -1e30f, -1e30f };   // running max for q = q0w + f*16 + lo
    float s_r[2] = { 0.f, 0.f };

    int kstart = q0w - (WIN - 1);
    if (kstart < 0) kstart = 0;
    kstart &= ~63;
    const int kend = q0w + 31;

    const unsigned short* kbase = qkv + (long)b * T_SEQ * NQKV + DM + hkv * HD;
    const unsigned short* vbase = vt + (long)(b * N_KV + hkv) * HD * T_SEQ;

    // staging offsets (pre-swizzled global source, linear LDS dest); 256 thr x 4 chunks each
    int kr[4], kc[4], vr[4], vc[4];
#pragma unroll
    for (int u = 0; u < 4; ++u) {
        const int c = u * 256 + tid;                       // 1024 chunks
        kr[u] = c >> 4;  kc[u] = (c & 15) ^ (kr[u] & 7);   // sK: 16 chunks/row
        vr[u] = c >> 3;  vc[u] = (c & 7) ^ (vr[u] & 7);    // sV: 8 chunks/row
    }

#define STAGE(bf, kt_) do {                                                              \
    _Pragma("unroll")                                                                    \
    for (int u = 0; u < 4; ++u) {                                                        \
        const int dbase = (u * 256 + w * 64) * 8;                                        \
        GLOAD_LDS16(kbase + (long)((kt_) + kr[u]) * NQKV + kc[u] * 8, &sK[bf][dbase]);   \
        GLOAD_LDS16(vbase + (long)vr[u] * T_SEQ + (kt_) + vc[u] * 8, &sV[bf][dbase]);    \
    } } while (0)

    STAGE(0, kstart);
    asm volatile("s_waitcnt vmcnt(0)" ::: "memory");
    __syncthreads();

    int buf = 0;
    for (int kt = kstart; kt <= kend; kt += 64) {
        if (kt + 64 <= kend) STAGE(buf ^ 1, kt + 64);

        // ---- swapped QK^T: sf[n][f] = S^T[key = kt+n*16+...][q = q0w+f*16+lo] ----
        f32x4 sf[4][2] = {};
        __builtin_amdgcn_s_setprio(1);
#pragma unroll
        for (int n = 0; n < 4; ++n) {
            const int row = n * 16 + lo;
#pragma unroll
            for (int s = 0; s < 4; ++s) {
                const int c = (s * 4 + hi) ^ (row & 7);
                bf16x8 kf = *(const bf16x8*)&sK[buf][row * 128 + c * 8];
                sf[n][0] = __builtin_amdgcn_mfma_f32_16x16x32_bf16(kf, qf2[0][s], sf[n][0], 0, 0, 0);
                sf[n][1] = __builtin_amdgcn_mfma_f32_16x16x32_bf16(kf, qf2[1][s], sf[n][1], 0, 0, 0);
            }
        }
        __builtin_amdgcn_s_setprio(0);

        // ---- lane-local online softmax, 2 q-frags ----
        float pv[2][4][4];
        float mx[2] = { -1e30f, -1e30f };
#pragma unroll
        for (int f = 0; f < 2; ++f) {
            const int q = q0w + f * 16 + lo;
#pragma unroll
            for (int n = 0; n < 4; ++n)
#pragma unroll
                for (int r = 0; r < 4; ++r) {
                    const int d = q - (kt + n * 16 + hi * 4 + r);
                    pv[f][n][r] = (d >= 0 && d < WIN) ? sf[n][f][r] : -1e30f;
                    mx[f] = fmaxf(mx[f], pv[f][n][r]);
                }
            mx[f] = fmaxf(mx[f], __shfl_xor(mx[f], 16));
            mx[f] = fmaxf(mx[f], __shfl_xor(mx[f], 32));
        }

        const bool ok = (mx[0] <= m_r[0] + 8.0f) && (mx[1] <= m_r[1] + 8.0f);
        if (!__all(ok)) {                          // defer-max: rescale rarely
#pragma unroll
            for (int f = 0; f < 2; ++f) {
                const float mnew = fmaxf(m_r[f], mx[f]);
                const float resc = exp2f(m_r[f] - mnew);
                s_r[f] *= resc;
                m_r[f] = mnew;
                float r4[4];
#pragma unroll
                for (int r = 0; r < 4; ++r) r4[r] = __shfl(resc, hi * 4 + r);
#pragma unroll
                for (int j = 0; j < 8; ++j) {
                    of[j][f][0] *= r4[0]; of[j][f][1] *= r4[1];
                    of[j][f][2] *= r4[2]; of[j][f][3] *= r4[3];
                }
            }
        }

#pragma unroll
        for (int f = 0; f < 2; ++f) {
            float psum = 0.f;
#pragma unroll
            for (int n = 0; n < 4; ++n)
#pragma unroll
                for (int r = 0; r < 4; ++r) {
                    pv[f][n][r] = exp2f(pv[f][n][r] - m_r[f]);
                    psum += pv[f][n][r];
                }
            psum += __shfl_xor(psum, 16);
            psum += __shfl_xor(psum, 32);
            s_r[f] += psum;
        }

        // ---- pack P -> per-wave swizzled LDS (u32 writes, cvt_pk) ----
        const int swz = (lo & 7) << 3;
#pragma unroll
        for (int f = 0; f < 2; ++f) {
            const int rowq = f * 16 + lo;
#pragma unroll
            for (int n = 0; n < 4; ++n) {
                const int k0 = n * 16 + hi * 4;
                *(unsigned*)&pl[rowq * 64 + (k0 ^ swz)]       = cvt_pk_bf16(pv[f][n][0], pv[f][n][1]);
                *(unsigned*)&pl[rowq * 64 + ((k0 + 2) ^ swz)] = cvt_pk_bf16(pv[f][n][2], pv[f][n][3]);
            }
        }
        asm volatile("s_waitcnt lgkmcnt(0)" ::: "memory");
        __builtin_amdgcn_sched_barrier(0);
        bf16x8 pa2[2][2];
#pragma unroll
        for (int f = 0; f < 2; ++f)
#pragma unroll
            for (int ks = 0; ks < 2; ++ks) {
                const int c = (ks * 4 + hi) ^ (lo & 7);
                pa2[f][ks] = *(const bf16x8*)&pl[(f * 16 + lo) * 64 + c * 8];
            }

        // ---- PV: of[j][f] += P[q-frag f] . V[d=j*16+lo] ----
        __builtin_amdgcn_s_setprio(1);
#pragma unroll
        for (int j = 0; j < 8; ++j) {
            const int row = j * 16 + lo;
#pragma unroll
            for (int ks = 0; ks < 2; ++ks) {
                const int c = (ks * 4 + hi) ^ (row & 7);
                bf16x8 vf = *(const bf16x8*)&sV[buf][row * 64 + c * 8];
                of[j][0] = __builtin_amdgcn_mfma_f32_16x16x32_bf16(pa2[0][ks], vf, of[j][0], 0, 0, 0);
                of[j][1] = __builtin_amdgcn_mfma_f32_16x16x32_bf16(pa2[1][ks], vf, of[j][1], 0, 0, 0);
            }
        }
        __builtin_amdgcn_s_setprio(0);

        asm volatile("s_waitcnt vmcnt(0)" ::: "memory");
        __syncthreads();
        buf ^= 1;
    }
#undef STAGE

#pragma unroll
    for (int f = 0; f < 2; ++f) {
        float s4[4];
#pragma unroll
        for (int r = 0; r < 4; ++r) s4[r] = __shfl(s_r[f], hi * 4 + r);
#pragma unroll
        for (int r = 0; r < 4; ++r) {
            const int qrow = q0w + f * 16 + hi * 4 + r;
            const float inv = 1.0f / s4[r];
            unsigned short* op = aout + (long)(b * T_SEQ + qrow) * DM + qh * HD + lo;
#pragma unroll
            for (int j = 0; j < 8; ++j) op[j * 16] = f2bf(of[j][f][r] * inv);
        }
    }
}

// ---------------- launch ----------------

extern "C" void kernel_launch(void* const* d_in, const int* in_sizes, int n_in,
                              void* d_out, int out_size, void* d_ws, size_t ws_size,
                              hipStream_t stream) {
    (void)in_sizes; (void)n_in; (void)out_size; (void)ws_size;
    const float* x  = (const float*)d_in[0];
    const float* wq = (const float*)d_in[1];
    const float* wk = (const float*)d_in[2];
    const float* wv = (const float*)d_in[3];
    const float* wo = (const float*)d_in[4];
    float* out = (float*)d_out;
    char* ws = (char*)d_ws;

    unsigned short* xbf   = (unsigned short*)(ws);                // 16,777,216 B
    unsigned short* wqkvT = (unsigned short*)(ws + 16777216);     // 12,582,912 B
    unsigned short* woT   = (unsigned short*)(ws + 29360128);     //  8,388,608 B
    unsigned short* qkv   = (unsigned short*)(ws + 37748736);     // 25,165,824 B
    unsigned short* vt    = (unsigned short*)(ws + 62914560);     //  4,194,304 B
    unsigned short* aout  = (unsigned short*)(ws + 67108864);     // 16,777,216 B
    float* cosT = (float*)(ws + 83886080);                        //    524,288 B
    float* sinT = (float*)(ws + 84410368);                        //    524,288 B

    prep_a<<<dim3(18944), dim3(256), 0, stream>>>(x, wq, wk, wv, wo, xbf, wqkvT, woT, cosT, sinT);
    gemm_bt<1><<<dim3(NQKV / 128, 32), dim3(256), 0, stream>>>(xbf, wqkvT, qkv, DM, NQKV);
    prep_b<<<dim3(7168), dim3(256), 0, stream>>>(qkv, cosT, sinT, vt);
    attn_kernel<<<dim3(T_SEQ / 32, 4, 2), dim3(256), 0, stream>>>(qkv, vt, aout);
    gemm_bt<0><<<dim3(DM / 128, 32), dim3(256), 0, stream>>>(aout, woT, out, DM, DM);
}

// Round 9
// 187.611 us; speedup vs baseline: 1.0012x; 1.0012x over previous
//
#include <hip/hip_runtime.h>

#define T_SEQ   2048
#define DM      2048
#define N_Q     16
#define N_KV    4
#define HD      128
#define WIN     512
#define NB      2
#define NQKV    3072
// 1/sqrt(128) * log2(e): attention computed in exp2 domain
#define QK_SCALE_L2E 0.12751744f

typedef short bf16x8 __attribute__((ext_vector_type(8)));
typedef float f32x4  __attribute__((ext_vector_type(4)));
typedef unsigned short us4v __attribute__((ext_vector_type(4)));

__device__ __forceinline__ unsigned short f2bf(float f) {
    union { float f; unsigned u; } v; v.f = f;
    unsigned u = v.u;
    u += 0x7fffu + ((u >> 16) & 1u);           // RNE
    return (unsigned short)(u >> 16);
}
__device__ __forceinline__ float bf2f(unsigned short h) {
    union { unsigned u; float f; } v; v.u = ((unsigned)h) << 16;
    return v.f;
}
__device__ __forceinline__ unsigned cvt_pk_bf16(float a, float b) {
    unsigned r;
    asm("v_cvt_pk_bf16_f32 %0, %1, %2" : "=v"(r) : "v"(a), "v"(b));
    return r;   // low16 = bf16(a), high16 = bf16(b)
}

#define GLOAD_LDS16(g, l) __builtin_amdgcn_global_load_lds( \
    (const __attribute__((address_space(1))) void*)(g),     \
    (__attribute__((address_space(3))) void*)(l), 16, 0, 0)

struct us4 { unsigned short a, b, c, d; };

// ---------------- fused prep A: x->bf16, 4 weight transposes, rope table ----------------
// flat grid: [0,8192) x-convert | [8192,18432) transposes | [18432,18944) rope table

__global__ __launch_bounds__(256)
void prep_a(const float* __restrict__ x, const float* __restrict__ wq,
            const float* __restrict__ wk, const float* __restrict__ wv,
            const float* __restrict__ wo,
            unsigned short* __restrict__ xbf, unsigned short* __restrict__ wqkvT,
            unsigned short* __restrict__ woT,
            float* __restrict__ cosT, float* __restrict__ sinT) {
    __shared__ float tile[32][33];
    int blk = blockIdx.x;
    if (blk < 8192) {                               // x: f32 -> bf16, 4 elems/thread
        long i = ((long)blk * 256 + threadIdx.x) * 4;
        float4 f = *(const float4*)(x + i);
        us4 o; o.a = f2bf(f.x); o.b = f2bf(f.y); o.c = f2bf(f.z); o.d = f2bf(f.w);
        *(us4*)(xbf + i) = o;
        return;
    }
    blk -= 8192;
    if (blk < 10240) {                              // weight transposes
        const float* in; unsigned short* outp; int C, bx, by;
        if (blk < 4096)      { in = wq; outp = wqkvT;                         C = DM;  bx = blk & 63;          by = blk >> 6; }
        else if (blk < 5120) { int k = blk - 4096; in = wk; outp = wqkvT + (long)DM * DM;         C = 512; bx = k & 15; by = k >> 4; }
        else if (blk < 6144) { int k = blk - 5120; in = wv; outp = wqkvT + (long)(DM + 512) * DM; C = 512; bx = k & 15; by = k >> 4; }
        else                 { int k = blk - 6144; in = wo; outp = woT;                           C = DM;  bx = k & 63; by = k >> 6; }
        const int c0 = bx * 32, r0 = by * 32;
        const int tx = threadIdx.x & 31, ty = threadIdx.x >> 5;
#pragma unroll
        for (int i = 0; i < 4; ++i)
            tile[ty + i * 8][tx] = in[(long)(r0 + ty + i * 8) * C + c0 + tx];
        __syncthreads();
#pragma unroll
        for (int i = 0; i < 4; ++i)
            outp[(long)(c0 + ty + i * 8) * DM + r0 + tx] = f2bf(tile[tx][ty + i * 8]);
        return;
    }
    blk -= 10240;                                   // rope table (512 blocks)
    const int idx = blk * 256 + threadIdx.x;        // < 2048*64
    const int t = idx >> 6, d = idx & 63;
    const float inv = __expf(-(float)d * (9.210340371976184f / 64.0f)); // 10000^(-d/64)
    const float ang = (float)t * inv;
    cosT[idx] = cosf(ang);
    sinT[idx] = sinf(ang);
}

// ---------------- fused prep B: rope apply (q,k) + v transpose ----------------
// flat grid: [0,5120) rope | [5120,7168) v-transpose

__global__ __launch_bounds__(256)
void prep_b(unsigned short* __restrict__ qkv,
            const float* __restrict__ cosT, const float* __restrict__ sinT,
            unsigned short* __restrict__ vt) {
    __shared__ unsigned short stile[32][33];
    int blk = blockIdx.x;
    if (blk < 5120) {                               // RoPE, 4 d-values/thread
        const int idx = blk * 256 + threadIdx.x;    // 4096*20*16
        const int d4 = (idx & 15) * 4;
        const int hh = (idx >> 4) % 20;
        const int row = idx / (16 * 20);
        const int t = row & (T_SEQ - 1);
        const int col = (hh < N_Q) ? hh * HD + d4 : DM + (hh - N_Q) * HD + d4;
        unsigned short* p = qkv + (long)row * NQKV + col;
        us4v a = *(const us4v*)p;
        us4v b = *(const us4v*)(p + 64);
        float4 c = *(const float4*)&cosT[t * 64 + d4];
        float4 s = *(const float4*)&sinT[t * 64 + d4];
        const float sc = (hh < N_Q) ? QK_SCALE_L2E : 1.0f;
        us4v o1, o2;
        const float cc[4] = { c.x, c.y, c.z, c.w }, ss[4] = { s.x, s.y, s.z, s.w };
#pragma unroll
        for (int i = 0; i < 4; ++i) {
            const float av = bf2f(a[i]), bv = bf2f(b[i]);
            o1[i] = f2bf((av * cc[i] - bv * ss[i]) * sc);
            o2[i] = f2bf((bv * cc[i] + av * ss[i]) * sc);
        }
        *(us4v*)p        = o1;
        *(us4v*)(p + 64) = o2;
        return;
    }
    blk -= 5120;                                    // v transpose (2048 blocks)
    const int bh = blk >> 8;                        // b*4 + hkv
    const int d0 = ((blk >> 6) & 3) * 32;
    const int t0 = (blk & 63) * 32;
    const int tx = threadIdx.x & 31, ty = threadIdx.x >> 5;
    const long inbase = (long)(bh >> 2) * T_SEQ;
    const int coff = DM + N_KV * HD + (bh & 3) * HD;   // 2560 + hkv*128
#pragma unroll
    for (int i = 0; i < 4; ++i)
        stile[ty + i * 8][tx] = qkv[(inbase + t0 + ty + i * 8) * NQKV + coff + d0 + tx];
    __syncthreads();
#pragma unroll
    for (int i = 0; i < 4; ++i)
        vt[((long)bh * HD + d0 + ty + i * 8) * T_SEQ + t0 + tx] = stile[tx][ty + i * 8];
}

// ---------------- GEMM: C[M][ldc] = A[M][K] * Bt[N][K]^T  (m97 structure + XCD swizzle) ----------------

template<int OUT_BF16>
__global__ __launch_bounds__(256)
void gemm_bt(const unsigned short* __restrict__ A,
             const unsigned short* __restrict__ Bt,
             void* __restrict__ Cvoid, int K, int ldc) {
    __shared__ __align__(16) unsigned short sA[128 * 64];
    __shared__ __align__(16) unsigned short sB[128 * 64];
    const int tid = threadIdx.x;
    const int lane = tid & 63;
    const int wid = tid >> 6;
    const int wr = (wid >> 1) * 64, wc = (wid & 1) * 64;

    // XCD-aware bijective swizzle (nwg divisible by 8 in all launches)
    const int gx = gridDim.x;
    const int nwg = gx * gridDim.y;
    int flat = blockIdx.y * gx + blockIdx.x;
    flat = (flat & 7) * (nwg >> 3) + (flat >> 3);
    const long Arow0 = (long)(flat / gx) * 128;
    const long Brow0 = (long)(flat % gx) * 128;

    f32x4 acc[4][4] = {};

    for (int kt = 0; kt < K; kt += 64) {
        __syncthreads();
#pragma unroll
        for (int n = 0; n < 4; ++n) {
            const int linb = n * 256 + wid * 64;      // wave-uniform 16B-chunk base
            const int lin  = linb + lane;             // this lane's chunk
            const int row  = lin >> 3;                // 8 chunks per 64-elem row
            const int sc   = (lin & 7) ^ (row & 7);   // pre-swizzled global source
            const unsigned short* gA = A  + (Arow0 + row) * K + kt + sc * 8;
            const unsigned short* gB = Bt + (Brow0 + row) * K + kt + sc * 8;
            GLOAD_LDS16(gA, &sA[linb * 8]);
            GLOAD_LDS16(gB, &sB[linb * 8]);
        }
        __syncthreads();
#pragma unroll
        for (int kk = 0; kk < 2; ++kk) {
            bf16x8 av[4], bv[4];
#pragma unroll
            for (int i = 0; i < 4; ++i) {
                const int row = wr + i * 16 + (lane & 15);
                const int c = (kk * 4 + (lane >> 4)) ^ (row & 7);
                av[i] = *(const bf16x8*)&sA[row * 64 + c * 8];
            }
#pragma unroll
            for (int j = 0; j < 4; ++j) {
                const int row = wc + j * 16 + (lane & 15);
                const int c = (kk * 4 + (lane >> 4)) ^ (row & 7);
                bv[j] = *(const bf16x8*)&sB[row * 64 + c * 8];
            }
#pragma unroll
            for (int i = 0; i < 4; ++i)
#pragma unroll
                for (int j = 0; j < 4; ++j)
                    acc[i][j] = __builtin_amdgcn_mfma_f32_16x16x32_bf16(av[i], bv[j], acc[i][j], 0, 0, 0);
        }
    }

    const int r0 = (int)Arow0 + wr + ((lane >> 4) << 2);
    const int c0 = (int)Brow0 + wc + (lane & 15);
    if (OUT_BF16) {
        unsigned short* C = (unsigned short*)Cvoid;
#pragma unroll
        for (int i = 0; i < 4; ++i)
#pragma unroll
            for (int j = 0; j < 4; ++j)
#pragma unroll
                for (int r = 0; r < 4; ++r)
                    C[(long)(r0 + i * 16 + r) * ldc + c0 + j * 16] = f2bf(acc[i][j][r]);
    } else {
        float* C = (float*)Cvoid;
#pragma unroll
        for (int i = 0; i < 4; ++i)
#pragma unroll
            for (int j = 0; j < 4; ++j)
#pragma unroll
                for (int r = 0; r < 4; ++r)
                    C[(long)(r0 + i * 16 + r) * ldc + c0 + j * 16] = acc[i][j][r];
    }
}

// ---------------- flash attention, sliding window ----------------
// grid (T/32, N_KV, B), 256 threads = 4 waves; wave w handles q-head hkv*4+w,
// q-rows qt*32 + [0,32) (2 q-frags). 4 waves share staged K/V tiles.
// LDS 80 KB -> 2 blocks/CU. Swapped QK^T, lane-local softmax, exp2 domain,
// defer-max, double-buffered K/V staging via global_load_lds.

__global__ __launch_bounds__(256)
void attn_kernel(const unsigned short* __restrict__ qkv,
                 const unsigned short* __restrict__ vt,
                 unsigned short* __restrict__ aout) {
    const int qt = blockIdx.x, hkv = blockIdx.y, b = blockIdx.z;
    const int tid = threadIdx.x, lane = tid & 63, w = tid >> 6;
    const int qh = hkv * 4 + w;                // q-head for this wave
    const int q0w = qt * 32;                   // block's first q-row
    const int lo = lane & 15, hi = lane >> 4;

    __shared__ __align__(16) unsigned short sK[2][64 * 128];   // [key][d], chunk-swizzled (32 KB)
    __shared__ __align__(16) unsigned short sV[2][128 * 64];   // [d][key], chunk-swizzled (32 KB)
    __shared__ __align__(16) unsigned short plds[4][32 * 64];  // per-wave P (16 KB)
    unsigned short* pl = plds[w];

    // Q fragments: 2 q-frags x 4 k-chunks
    bf16x8 qf2[2][4];
#pragma unroll
    for (int f = 0; f < 2; ++f) {
        const unsigned short* qp = qkv + (long)(b * T_SEQ + q0w + f * 16 + lo) * NQKV + qh * HD + hi * 8;
#pragma unroll
        for (int s = 0; s < 4; ++s) qf2[f][s] = *(const bf16x8*)(qp + s * 32);
    }

    f32x4 of[8][2] = {};
    float m_r[2] = { -1e30f, -1e30f };   // running max for q = q0w + f*16 + lo
    float s_r[2] = { 0.f, 0.f };

    int kstart = q0w - (WIN - 1);
    if (kstart < 0) kstart = 0;
    kstart &= ~63;
    const int kend = q0w + 31;

    const unsigned short* kbase = qkv + (long)b * T_SEQ * NQKV + DM + hkv * HD;
    const unsigned short* vbase = vt + (long)(b * N_KV + hkv) * HD * T_SEQ;

    // staging offsets (pre-swizzled global source, linear LDS dest); 256 thr x 4 chunks each
    int kr[4], kc[4], vr[4], vc[4];
#pragma unroll
    for (int u = 0; u < 4; ++u) {
        const int c = u * 256 + tid;                       // 1024 chunks
        kr[u] = c >> 4;  kc[u] = (c & 15) ^ (kr[u] & 7);   // sK: 16 chunks/row
        vr[u] = c >> 3;  vc[u] = (c & 7) ^ (vr[u] & 7);    // sV: 8 chunks/row
    }

#define STAGE(bf, kt_) do {                                                              \
    _Pragma("unroll")                                                                    \
    for (int u = 0; u < 4; ++u) {                                                        \
        const int dbase = (u * 256 + w * 64) * 8;                                        \
        GLOAD_LDS16(kbase + (long)((kt_) + kr[u]) * NQKV + kc[u] * 8, &sK[bf][dbase]);   \
        GLOAD_LDS16(vbase + (long)vr[u] * T_SEQ + (kt_) + vc[u] * 8, &sV[bf][dbase]);    \
    } } while (0)

    STAGE(0, kstart);
    asm volatile("s_waitcnt vmcnt(0)" ::: "memory");
    __syncthreads();

    int buf = 0;
    for (int kt = kstart; kt <= kend; kt += 64) {
        if (kt + 64 <= kend) STAGE(buf ^ 1, kt + 64);

        // ---- swapped QK^T: sf[n][f] = S^T[key = kt+n*16+...][q = q0w+f*16+lo] ----
        f32x4 sf[4][2] = {};
        __builtin_amdgcn_s_setprio(1);
#pragma unroll
        for (int n = 0; n < 4; ++n) {
            const int row = n * 16 + lo;
#pragma unroll
            for (int s = 0; s < 4; ++s) {
                const int c = (s * 4 + hi) ^ (row & 7);
                bf16x8 kf = *(const bf16x8*)&sK[buf][row * 128 + c * 8];
                sf[n][0] = __builtin_amdgcn_mfma_f32_16x16x32_bf16(kf, qf2[0][s], sf[n][0], 0, 0, 0);
                sf[n][1] = __builtin_amdgcn_mfma_f32_16x16x32_bf16(kf, qf2[1][s], sf[n][1], 0, 0, 0);
            }
        }
        __builtin_amdgcn_s_setprio(0);

        // ---- lane-local online softmax, 2 q-frags ----
        float pv[2][4][4];
        float mx[2] = { -1e30f, -1e30f };
#pragma unroll
        for (int f = 0; f < 2; ++f) {
            const int q = q0w + f * 16 + lo;
#pragma unroll
            for (int n = 0; n < 4; ++n)
#pragma unroll
                for (int r = 0; r < 4; ++r) {
                    const int d = q - (kt + n * 16 + hi * 4 + r);
                    pv[f][n][r] = (d >= 0 && d < WIN) ? sf[n][f][r] : -1e30f;
                    mx[f] = fmaxf(mx[f], pv[f][n][r]);
                }
            mx[f] = fmaxf(mx[f], __shfl_xor(mx[f], 16));
            mx[f] = fmaxf(mx[f], __shfl_xor(mx[f], 32));
        }

        const bool ok = (mx[0] <= m_r[0] + 8.0f) && (mx[1] <= m_r[1] + 8.0f);
        if (!__all(ok)) {                          // defer-max: rescale rarely
#pragma unroll
            for (int f = 0; f < 2; ++f) {
                const float mnew = fmaxf(m_r[f], mx[f]);
                const float resc = exp2f(m_r[f] - mnew);
                s_r[f] *= resc;
                m_r[f] = mnew;
                float r4[4];
#pragma unroll
                for (int r = 0; r < 4; ++r) r4[r] = __shfl(resc, hi * 4 + r);
#pragma unroll
                for (int j = 0; j < 8; ++j) {
                    of[j][f][0] *= r4[0]; of[j][f][1] *= r4[1];
                    of[j][f][2] *= r4[2]; of[j][f][3] *= r4[3];
                }
            }
        }

#pragma unroll
        for (int f = 0; f < 2; ++f) {
            float psum = 0.f;
#pragma unroll
            for (int n = 0; n < 4; ++n)
#pragma unroll
                for (int r = 0; r < 4; ++r) {
                    pv[f][n][r] = exp2f(pv[f][n][r] - m_r[f]);
                    psum += pv[f][n][r];
                }
            psum += __shfl_xor(psum, 16);
            psum += __shfl_xor(psum, 32);
            s_r[f] += psum;
        }

        // ---- pack P -> per-wave swizzled LDS (u32 writes, cvt_pk) ----
        const int swz = (lo & 7) << 3;
#pragma unroll
        for (int f = 0; f < 2; ++f) {
            const int rowq = f * 16 + lo;
#pragma unroll
            for (int n = 0; n < 4; ++n) {
                const int k0 = n * 16 + hi * 4;
                *(unsigned*)&pl[rowq * 64 + (k0 ^ swz)]       = cvt_pk_bf16(pv[f][n][0], pv[f][n][1]);
                *(unsigned*)&pl[rowq * 64 + ((k0 + 2) ^ swz)] = cvt_pk_bf16(pv[f][n][2], pv[f][n][3]);
            }
        }
        asm volatile("s_waitcnt lgkmcnt(0)" ::: "memory");
        __builtin_amdgcn_sched_barrier(0);
        bf16x8 pa2[2][2];
#pragma unroll
        for (int f = 0; f < 2; ++f)
#pragma unroll
            for (int ks = 0; ks < 2; ++ks) {
                const int c = (ks * 4 + hi) ^ (lo & 7);
                pa2[f][ks] = *(const bf16x8*)&pl[(f * 16 + lo) * 64 + c * 8];
            }

        // ---- PV: of[j][f] += P[q-frag f] . V[d=j*16+lo] ----
        __builtin_amdgcn_s_setprio(1);
#pragma unroll
        for (int j = 0; j < 8; ++j) {
            const int row = j * 16 + lo;
#pragma unroll
            for (int ks = 0; ks < 2; ++ks) {
                const int c = (ks * 4 + hi) ^ (row & 7);
                bf16x8 vf = *(const bf16x8*)&sV[buf][row * 64 + c * 8];
                of[j][0] = __builtin_amdgcn_mfma_f32_16x16x32_bf16(pa2[0][ks], vf, of[j][0], 0, 0, 0);
                of[j][1] = __builtin_amdgcn_mfma_f32_16x16x32_bf16(pa2[1][ks], vf, of[j][1], 0, 0, 0);
            }
        }
        __builtin_amdgcn_s_setprio(0);

        asm volatile("s_waitcnt vmcnt(0)" ::: "memory");
        __syncthreads();
        buf ^= 1;
    }
#undef STAGE

#pragma unroll
    for (int f = 0; f < 2; ++f) {
        float s4[4];
#pragma unroll
        for (int r = 0; r < 4; ++r) s4[r] = __shfl(s_r[f], hi * 4 + r);
#pragma unroll
        for (int r = 0; r < 4; ++r) {
            const int qrow = q0w + f * 16 + hi * 4 + r;
            const float inv = 1.0f / s4[r];
            unsigned short* op = aout + (long)(b * T_SEQ + qrow) * DM + qh * HD + lo;
#pragma unroll
            for (int j = 0; j < 8; ++j) op[j * 16] = f2bf(of[j][f][r] * inv);
        }
    }
}

// ---------------- launch ----------------

extern "C" void kernel_launch(void* const* d_in, const int* in_sizes, int n_in,
                              void* d_out, int out_size, void* d_ws, size_t ws_size,
                              hipStream_t stream) {
    (void)in_sizes; (void)n_in; (void)out_size; (void)ws_size;
    const float* x  = (const float*)d_in[0];
    const float* wq = (const float*)d_in[1];
    const float* wk = (const float*)d_in[2];
    const float* wv = (const float*)d_in[3];
    const float* wo = (const float*)d_in[4];
    float* out = (float*)d_out;
    char* ws = (char*)d_ws;

    unsigned short* xbf   = (unsigned short*)(ws);                // 16,777,216 B
    unsigned short* wqkvT = (unsigned short*)(ws + 16777216);     // 12,582,912 B
    unsigned short* woT   = (unsigned short*)(ws + 29360128);     //  8,388,608 B
    unsigned short* qkv   = (unsigned short*)(ws + 37748736);     // 25,165,824 B
    unsigned short* vt    = (unsigned short*)(ws + 62914560);     //  4,194,304 B
    unsigned short* aout  = (unsigned short*)(ws + 67108864);     // 16,777,216 B
    float* cosT = (float*)(ws + 83886080);                        //    524,288 B
    float* sinT = (float*)(ws + 84410368);                        //    524,288 B

    prep_a<<<dim3(18944), dim3(256), 0, stream>>>(x, wq, wk, wv, wo, xbf, wqkvT, woT, cosT, sinT);
    gemm_bt<1><<<dim3(NQKV / 128, 32), dim3(256), 0, stream>>>(xbf, wqkvT, qkv, DM, NQKV);
    prep_b<<<dim3(7168), dim3(256), 0, stream>>>(qkv, cosT, sinT, vt);
    attn_kernel<<<dim3(T_SEQ / 32, 4, 2), dim3(256), 0, stream>>>(qkv, vt, aout);
    gemm_bt<0><<<dim3(DM / 128, 32), dim3(256), 0, stream>>>(aout, woT, out, DM, DM);
}

// Round 10
// 168.027 us; speedup vs baseline: 1.1179x; 1.1166x over previous
//
#include <hip/hip_runtime.h>

#define T_SEQ   2048
#define DM      2048
#define N_Q     16
#define N_KV    4
#define HD      128
#define WIN     512
#define NB      2
#define NQKV    3072
// 1/sqrt(128) * log2(e): attention computed in exp2 domain
#define QK_SCALE_L2E 0.12751744f

typedef short bf16x8 __attribute__((ext_vector_type(8)));
typedef float f32x4  __attribute__((ext_vector_type(4)));
typedef unsigned short us4v __attribute__((ext_vector_type(4)));

__device__ __forceinline__ unsigned short f2bf(float f) {
    union { float f; unsigned u; } v; v.f = f;
    unsigned u = v.u;
    u += 0x7fffu + ((u >> 16) & 1u);           // RNE
    return (unsigned short)(u >> 16);
}
__device__ __forceinline__ float bf2f(unsigned short h) {
    union { unsigned u; float f; } v; v.u = ((unsigned)h) << 16;
    return v.f;
}
__device__ __forceinline__ unsigned cvt_pk_bf16(float a, float b) {
    unsigned r;
    asm("v_cvt_pk_bf16_f32 %0, %1, %2" : "=v"(r) : "v"(a), "v"(b));
    return r;   // low16 = bf16(a), high16 = bf16(b)
}

#define GLOAD_LDS16(g, l) __builtin_amdgcn_global_load_lds( \
    (const __attribute__((address_space(1))) void*)(g),     \
    (__attribute__((address_space(3))) void*)(l), 16, 0, 0)

struct us4 { unsigned short a, b, c, d; };

// ---------------- fused prep A: x->bf16, 4 weight transposes, rope table ----------------
// flat grid: [0,8192) x-convert | [8192,18432) transposes | [18432,18944) rope table

__global__ __launch_bounds__(256)
void prep_a(const float* __restrict__ x, const float* __restrict__ wq,
            const float* __restrict__ wk, const float* __restrict__ wv,
            const float* __restrict__ wo,
            unsigned short* __restrict__ xbf, unsigned short* __restrict__ wqkvT,
            unsigned short* __restrict__ woT,
            float* __restrict__ cosT, float* __restrict__ sinT) {
    __shared__ float tile[32][33];
    int blk = blockIdx.x;
    if (blk < 8192) {                               // x: f32 -> bf16, 4 elems/thread
        long i = ((long)blk * 256 + threadIdx.x) * 4;
        float4 f = *(const float4*)(x + i);
        us4 o; o.a = f2bf(f.x); o.b = f2bf(f.y); o.c = f2bf(f.z); o.d = f2bf(f.w);
        *(us4*)(xbf + i) = o;
        return;
    }
    blk -= 8192;
    if (blk < 10240) {                              // weight transposes
        const float* in; unsigned short* outp; int C, bx, by;
        if (blk < 4096)      { in = wq; outp = wqkvT;                         C = DM;  bx = blk & 63;          by = blk >> 6; }
        else if (blk < 5120) { int k = blk - 4096; in = wk; outp = wqkvT + (long)DM * DM;         C = 512; bx = k & 15; by = k >> 4; }
        else if (blk < 6144) { int k = blk - 5120; in = wv; outp = wqkvT + (long)(DM + 512) * DM; C = 512; bx = k & 15; by = k >> 4; }
        else                 { int k = blk - 6144; in = wo; outp = woT;                           C = DM;  bx = k & 63; by = k >> 6; }
        const int c0 = bx * 32, r0 = by * 32;
        const int tx = threadIdx.x & 31, ty = threadIdx.x >> 5;
#pragma unroll
        for (int i = 0; i < 4; ++i)
            tile[ty + i * 8][tx] = in[(long)(r0 + ty + i * 8) * C + c0 + tx];
        __syncthreads();
#pragma unroll
        for (int i = 0; i < 4; ++i)
            outp[(long)(c0 + ty + i * 8) * DM + r0 + tx] = f2bf(tile[tx][ty + i * 8]);
        return;
    }
    blk -= 10240;                                   // rope table (512 blocks)
    const int idx = blk * 256 + threadIdx.x;        // < 2048*64
    const int t = idx >> 6, d = idx & 63;
    const float inv = __expf(-(float)d * (9.210340371976184f / 64.0f)); // 10000^(-d/64)
    const float ang = (float)t * inv;
    cosT[idx] = cosf(ang);
    sinT[idx] = sinf(ang);
}

// ---------------- fused prep B: rope apply (q,k) + v transpose ----------------
// flat grid: [0,5120) rope | [5120,7168) v-transpose

__global__ __launch_bounds__(256)
void prep_b(unsigned short* __restrict__ qkv,
            const float* __restrict__ cosT, const float* __restrict__ sinT,
            unsigned short* __restrict__ vt) {
    __shared__ unsigned short stile[32][33];
    int blk = blockIdx.x;
    if (blk < 5120) {                               // RoPE, 4 d-values/thread
        const int idx = blk * 256 + threadIdx.x;    // 4096*20*16
        const int d4 = (idx & 15) * 4;
        const int hh = (idx >> 4) % 20;
        const int row = idx / (16 * 20);
        const int t = row & (T_SEQ - 1);
        const int col = (hh < N_Q) ? hh * HD + d4 : DM + (hh - N_Q) * HD + d4;
        unsigned short* p = qkv + (long)row * NQKV + col;
        us4v a = *(const us4v*)p;
        us4v b = *(const us4v*)(p + 64);
        float4 c = *(const float4*)&cosT[t * 64 + d4];
        float4 s = *(const float4*)&sinT[t * 64 + d4];
        const float sc = (hh < N_Q) ? QK_SCALE_L2E : 1.0f;
        us4v o1, o2;
        const float cc[4] = { c.x, c.y, c.z, c.w }, ss[4] = { s.x, s.y, s.z, s.w };
#pragma unroll
        for (int i = 0; i < 4; ++i) {
            const float av = bf2f(a[i]), bv = bf2f(b[i]);
            o1[i] = f2bf((av * cc[i] - bv * ss[i]) * sc);
            o2[i] = f2bf((bv * cc[i] + av * ss[i]) * sc);
        }
        *(us4v*)p        = o1;
        *(us4v*)(p + 64) = o2;
        return;
    }
    blk -= 5120;                                    // v transpose (2048 blocks)
    const int bh = blk >> 8;                        // b*4 + hkv
    const int d0 = ((blk >> 6) & 3) * 32;
    const int t0 = (blk & 63) * 32;
    const int tx = threadIdx.x & 31, ty = threadIdx.x >> 5;
    const long inbase = (long)(bh >> 2) * T_SEQ;
    const int coff = DM + N_KV * HD + (bh & 3) * HD;   // 2560 + hkv*128
#pragma unroll
    for (int i = 0; i < 4; ++i)
        stile[ty + i * 8][tx] = qkv[(inbase + t0 + ty + i * 8) * NQKV + coff + d0 + tx];
    __syncthreads();
#pragma unroll
    for (int i = 0; i < 4; ++i)
        vt[((long)bh * HD + d0 + ty + i * 8) * T_SEQ + t0 + tx] = stile[tx][ty + i * 8];
}

// ---------------- GEMM: C[M][ldc] = A[M][K] * Bt[N][K]^T  (m97 structure + XCD swizzle) ----------------

template<int OUT_BF16>
__global__ __launch_bounds__(256)
void gemm_bt(const unsigned short* __restrict__ A,
             const unsigned short* __restrict__ Bt,
             void* __restrict__ Cvoid, int K, int ldc) {
    __shared__ __align__(16) unsigned short sA[128 * 64];
    __shared__ __align__(16) unsigned short sB[128 * 64];
    const int tid = threadIdx.x;
    const int lane = tid & 63;
    const int wid = tid >> 6;
    const int wr = (wid >> 1) * 64, wc = (wid & 1) * 64;

    // XCD-aware bijective swizzle (nwg divisible by 8 in all launches)
    const int gx = gridDim.x;
    const int nwg = gx * gridDim.y;
    int flat = blockIdx.y * gx + blockIdx.x;
    flat = (flat & 7) * (nwg >> 3) + (flat >> 3);
    const long Arow0 = (long)(flat / gx) * 128;
    const long Brow0 = (long)(flat % gx) * 128;

    f32x4 acc[4][4] = {};

    for (int kt = 0; kt < K; kt += 64) {
        __syncthreads();
#pragma unroll
        for (int n = 0; n < 4; ++n) {
            const int linb = n * 256 + wid * 64;      // wave-uniform 16B-chunk base
            const int lin  = linb + lane;             // this lane's chunk
            const int row  = lin >> 3;                // 8 chunks per 64-elem row
            const int sc   = (lin & 7) ^ (row & 7);   // pre-swizzled global source
            const unsigned short* gA = A  + (Arow0 + row) * K + kt + sc * 8;
            const unsigned short* gB = Bt + (Brow0 + row) * K + kt + sc * 8;
            GLOAD_LDS16(gA, &sA[linb * 8]);
            GLOAD_LDS16(gB, &sB[linb * 8]);
        }
        __syncthreads();
#pragma unroll
        for (int kk = 0; kk < 2; ++kk) {
            bf16x8 av[4], bv[4];
#pragma unroll
            for (int i = 0; i < 4; ++i) {
                const int row = wr + i * 16 + (lane & 15);
                const int c = (kk * 4 + (lane >> 4)) ^ (row & 7);
                av[i] = *(const bf16x8*)&sA[row * 64 + c * 8];
            }
#pragma unroll
            for (int j = 0; j < 4; ++j) {
                const int row = wc + j * 16 + (lane & 15);
                const int c = (kk * 4 + (lane >> 4)) ^ (row & 7);
                bv[j] = *(const bf16x8*)&sB[row * 64 + c * 8];
            }
#pragma unroll
            for (int i = 0; i < 4; ++i)
#pragma unroll
                for (int j = 0; j < 4; ++j)
                    acc[i][j] = __builtin_amdgcn_mfma_f32_16x16x32_bf16(av[i], bv[j], acc[i][j], 0, 0, 0);
        }
    }

    const int r0 = (int)Arow0 + wr + ((lane >> 4) << 2);
    const int c0 = (int)Brow0 + wc + (lane & 15);
    if (OUT_BF16) {
        unsigned short* C = (unsigned short*)Cvoid;
#pragma unroll
        for (int i = 0; i < 4; ++i)
#pragma unroll
            for (int j = 0; j < 4; ++j)
#pragma unroll
                for (int r = 0; r < 4; ++r)
                    C[(long)(r0 + i * 16 + r) * ldc + c0 + j * 16] = f2bf(acc[i][j][r]);
    } else {
        float* C = (float*)Cvoid;
#pragma unroll
        for (int i = 0; i < 4; ++i)
#pragma unroll
            for (int j = 0; j < 4; ++j)
#pragma unroll
                for (int r = 0; r < 4; ++r)
                    C[(long)(r0 + i * 16 + r) * ldc + c0 + j * 16] = acc[i][j][r];
    }
}

// ---------------- flash attention, sliding window ----------------
// grid (T/64, N_KV, B), 512 threads = 8 waves.
// wave w: q-head = hkv*4 + (w&3), q-rows = qt*64 + (w>>2)*32 + [0,32).
// All 8 waves share the staged K/V tiles (4 q-heads x 2 q-halves).
// Swapped QK^T (S^T in regs, lane-local softmax), exp2 domain, defer-max,
// double-buffered K/V staging via global_load_lds.

__global__ __launch_bounds__(512, 2)
void attn_kernel(const unsigned short* __restrict__ qkv,
                 const unsigned short* __restrict__ vt,
                 unsigned short* __restrict__ aout) {
    const int qt = blockIdx.x, hkv = blockIdx.y, b = blockIdx.z;
    const int tid = threadIdx.x, lane = tid & 63, w = tid >> 6;
    const int qh = hkv * 4 + (w & 3);          // q-head for this wave
    const int qsub = w >> 2;                   // 0 or 1: which 32-row half
    const int q0w = qt * 64 + qsub * 32;       // wave's first q-row
    const int lo = lane & 15, hi = lane >> 4;

    __shared__ __align__(16) unsigned short sK[2][64 * 128];   // [key][d], chunk-swizzled
    __shared__ __align__(16) unsigned short sV[2][128 * 64];   // [d][key], chunk-swizzled
    __shared__ __align__(16) unsigned short plds[8][32 * 64];  // per-wave P, [q][key^swz]
    unsigned short* pl = plds[w];

    // Q fragments: 2 q-frags x 4 k-chunks
    bf16x8 qf2[2][4];
#pragma unroll
    for (int f = 0; f < 2; ++f) {
        const unsigned short* qp = qkv + (long)(b * T_SEQ + q0w + f * 16 + lo) * NQKV + qh * HD + hi * 8;
#pragma unroll
        for (int s = 0; s < 4; ++s) qf2[f][s] = *(const bf16x8*)(qp + s * 32);
    }

    f32x4 of[8][2] = {};
    float m_r[2] = { -1e30f, -1e30f };   // running max for q = q0w + f*16 + lo
    float s_r[2] = { 0.f, 0.f };

    int kstart = qt * 64 - (WIN - 1);
    if (kstart < 0) kstart = 0;
    kstart &= ~63;
    const int kend = qt * 64 + 63;

    const unsigned short* kbase = qkv + (long)b * T_SEQ * NQKV + DM + hkv * HD;
    const unsigned short* vbase = vt + (long)(b * N_KV + hkv) * HD * T_SEQ;

    // staging offsets (pre-swizzled global source, linear LDS dest); 512 thr x 2 chunks each
    int kr[2], kc[2], vr[2], vc[2];
#pragma unroll
    for (int u = 0; u < 2; ++u) {
        const int c = u * 512 + tid;
        kr[u] = c >> 4;  kc[u] = (c & 15) ^ (kr[u] & 7);   // sK: 16 chunks/row
        vr[u] = c >> 3;  vc[u] = (c & 7) ^ (vr[u] & 7);    // sV: 8 chunks/row
    }

#define STAGE(bf, kt_) do {                                                              \
    _Pragma("unroll")                                                                    \
    for (int u = 0; u < 2; ++u) {                                                        \
        const int dbase = (u * 512 + w * 64) * 8;                                        \
        GLOAD_LDS16(kbase + (long)((kt_) + kr[u]) * NQKV + kc[u] * 8, &sK[bf][dbase]);   \
        GLOAD_LDS16(vbase + (long)vr[u] * T_SEQ + (kt_) + vc[u] * 8, &sV[bf][dbase]);    \
    } } while (0)

    STAGE(0, kstart);
    asm volatile("s_waitcnt vmcnt(0)" ::: "memory");
    __syncthreads();

    int buf = 0;
    for (int kt = kstart; kt <= kend; kt += 64) {
        if (kt + 64 <= kend) STAGE(buf ^ 1, kt + 64);

        // ---- swapped QK^T: sf[n][f] = S^T[key = kt+n*16+...][q = q0w+f*16+lo] ----
        f32x4 sf[4][2] = {};
        __builtin_amdgcn_s_setprio(1);
#pragma unroll
        for (int n = 0; n < 4; ++n) {
            const int row = n * 16 + lo;
#pragma unroll
            for (int s = 0; s < 4; ++s) {
                const int c = (s * 4 + hi) ^ (row & 7);
                bf16x8 kf = *(const bf16x8*)&sK[buf][row * 128 + c * 8];
                sf[n][0] = __builtin_amdgcn_mfma_f32_16x16x32_bf16(kf, qf2[0][s], sf[n][0], 0, 0, 0);
                sf[n][1] = __builtin_amdgcn_mfma_f32_16x16x32_bf16(kf, qf2[1][s], sf[n][1], 0, 0, 0);
            }
        }
        __builtin_amdgcn_s_setprio(0);

        // ---- lane-local online softmax, 2 q-frags ----
        float pv[2][4][4];
        float mx[2] = { -1e30f, -1e30f };
#pragma unroll
        for (int f = 0; f < 2; ++f) {
            const int q = q0w + f * 16 + lo;
#pragma unroll
            for (int n = 0; n < 4; ++n)
#pragma unroll
                for (int r = 0; r < 4; ++r) {
                    const int d = q - (kt + n * 16 + hi * 4 + r);
                    pv[f][n][r] = (d >= 0 && d < WIN) ? sf[n][f][r] : -1e30f;
                    mx[f] = fmaxf(mx[f], pv[f][n][r]);
                }
            mx[f] = fmaxf(mx[f], __shfl_xor(mx[f], 16));
            mx[f] = fmaxf(mx[f], __shfl_xor(mx[f], 32));
        }

        const bool ok = (mx[0] <= m_r[0] + 8.0f) && (mx[1] <= m_r[1] + 8.0f);
        if (!__all(ok)) {                          // defer-max: rescale rarely
#pragma unroll
            for (int f = 0; f < 2; ++f) {
                const float mnew = fmaxf(m_r[f], mx[f]);
                const float resc = exp2f(m_r[f] - mnew);
                s_r[f] *= resc;
                m_r[f] = mnew;
                float r4[4];
#pragma unroll
                for (int r = 0; r < 4; ++r) r4[r] = __shfl(resc, hi * 4 + r);
#pragma unroll
                for (int j = 0; j < 8; ++j) {
                    of[j][f][0] *= r4[0]; of[j][f][1] *= r4[1];
                    of[j][f][2] *= r4[2]; of[j][f][3] *= r4[3];
                }
            }
        }

#pragma unroll
        for (int f = 0; f < 2; ++f) {
            float psum = 0.f;
#pragma unroll
            for (int n = 0; n < 4; ++n)
#pragma unroll
                for (int r = 0; r < 4; ++r) {
                    pv[f][n][r] = exp2f(pv[f][n][r] - m_r[f]);
                    psum += pv[f][n][r];
                }
            psum += __shfl_xor(psum, 16);
            psum += __shfl_xor(psum, 32);
            s_r[f] += psum;
        }

        // ---- pack P -> per-wave swizzled LDS (u32 writes, cvt_pk) ----
        const int swz = (lo & 7) << 3;
#pragma unroll
        for (int f = 0; f < 2; ++f) {
            const int rowq = f * 16 + lo;
#pragma unroll
            for (int n = 0; n < 4; ++n) {
                const int k0 = n * 16 + hi * 4;
                *(unsigned*)&pl[rowq * 64 + (k0 ^ swz)]       = cvt_pk_bf16(pv[f][n][0], pv[f][n][1]);
                *(unsigned*)&pl[rowq * 64 + ((k0 + 2) ^ swz)] = cvt_pk_bf16(pv[f][n][2], pv[f][n][3]);
            }
        }
        asm volatile("s_waitcnt lgkmcnt(0)" ::: "memory");
        __builtin_amdgcn_sched_barrier(0);
        bf16x8 pa2[2][2];
#pragma unroll
        for (int f = 0; f < 2; ++f)
#pragma unroll
            for (int ks = 0; ks < 2; ++ks) {
                const int c = (ks * 4 + hi) ^ (lo & 7);
                pa2[f][ks] = *(const bf16x8*)&pl[(f * 16 + lo) * 64 + c * 8];
            }

        // ---- PV: of[j][f] += P[q-frag f] . V[d=j*16+lo] ----
        __builtin_amdgcn_s_setprio(1);
#pragma unroll
        for (int j = 0; j < 8; ++j) {
            const int row = j * 16 + lo;
#pragma unroll
            for (int ks = 0; ks < 2; ++ks) {
                const int c = (ks * 4 + hi) ^ (row & 7);
                bf16x8 vf = *(const bf16x8*)&sV[buf][row * 64 + c * 8];
                of[j][0] = __builtin_amdgcn_mfma_f32_16x16x32_bf16(pa2[0][ks], vf, of[j][0], 0, 0, 0);
                of[j][1] = __builtin_amdgcn_mfma_f32_16x16x32_bf16(pa2[1][ks], vf, of[j][1], 0, 0, 0);
            }
        }
        __builtin_amdgcn_s_setprio(0);

        asm volatile("s_waitcnt vmcnt(0)" ::: "memory");
        __syncthreads();
        buf ^= 1;
    }
#undef STAGE

#pragma unroll
    for (int f = 0; f < 2; ++f) {
        float s4[4];
#pragma unroll
        for (int r = 0; r < 4; ++r) s4[r] = __shfl(s_r[f], hi * 4 + r);
#pragma unroll
        for (int r = 0; r < 4; ++r) {
            const int qrow = q0w + f * 16 + hi * 4 + r;
            const float inv = 1.0f / s4[r];
            unsigned short* op = aout + (long)(b * T_SEQ + qrow) * DM + qh * HD + lo;
#pragma unroll
            for (int j = 0; j < 8; ++j) op[j * 16] = f2bf(of[j][f][r] * inv);
        }
    }
}

// ---------------- launch ----------------

extern "C" void kernel_launch(void* const* d_in, const int* in_sizes, int n_in,
                              void* d_out, int out_size, void* d_ws, size_t ws_size,
                              hipStream_t stream) {
    (void)in_sizes; (void)n_in; (void)out_size; (void)ws_size;
    const float* x  = (const float*)d_in[0];
    const float* wq = (const float*)d_in[1];
    const float* wk = (const float*)d_in[2];
    const float* wv = (const float*)d_in[3];
    const float* wo = (const float*)d_in[4];
    float* out = (float*)d_out;
    char* ws = (char*)d_ws;

    unsigned short* xbf   = (unsigned short*)(ws);                // 16,777,216 B
    unsigned short* wqkvT = (unsigned short*)(ws + 16777216);     // 12,582,912 B
    unsigned short* woT   = (unsigned short*)(ws + 29360128);     //  8,388,608 B
    unsigned short* qkv   = (unsigned short*)(ws + 37748736);     // 25,165,824 B
    unsigned short* vt    = (unsigned short*)(ws + 62914560);     //  4,194,304 B
    unsigned short* aout  = (unsigned short*)(ws + 67108864);     // 16,777,216 B
    float* cosT = (float*)(ws + 83886080);                        //    524,288 B
    float* sinT = (float*)(ws + 84410368);                        //    524,288 B

    prep_a<<<dim3(18944), dim3(256), 0, stream>>>(x, wq, wk, wv, wo, xbf, wqkvT, woT, cosT, sinT);
    gemm_bt<1><<<dim3(NQKV / 128, 32), dim3(256), 0, stream>>>(xbf, wqkvT, qkv, DM, NQKV);
    prep_b<<<dim3(7168), dim3(256), 0, stream>>>(qkv, cosT, sinT, vt);
    attn_kernel<<<dim3(T_SEQ / 64, 4, 2), dim3(512), 0, stream>>>(qkv, vt, aout);
    gemm_bt<0><<<dim3(DM / 128, 32), dim3(256), 0, stream>>>(aout, woT, out, DM, DM);
}

// Round 12
// 162.813 us; speedup vs baseline: 1.1537x; 1.0320x over previous
//
#include <hip/hip_runtime.h>

#define T_SEQ   2048
#define DM      2048
#define N_Q     16
#define N_KV    4
#define HD      128
#define WIN     512
#define NB      2
#define NQKV    3072
// 1/sqrt(128) * log2(e): attention computed in exp2 domain
#define QK_SCALE_L2E 0.12751744f

typedef short bf16x8 __attribute__((ext_vector_type(8)));
typedef float f32x4  __attribute__((ext_vector_type(4)));
typedef float f32x16 __attribute__((ext_vector_type(16)));
typedef unsigned short us4v __attribute__((ext_vector_type(4)));

__device__ __forceinline__ unsigned short f2bf(float f) {
    union { float f; unsigned u; } v; v.f = f;
    unsigned u = v.u;
    u += 0x7fffu + ((u >> 16) & 1u);           // RNE
    return (unsigned short)(u >> 16);
}
__device__ __forceinline__ float bf2f(unsigned short h) {
    union { unsigned u; float f; } v; v.u = ((unsigned)h) << 16;
    return v.f;
}
__device__ __forceinline__ unsigned cvt_pk_bf16(float a, float b) {
    unsigned r;
    asm("v_cvt_pk_bf16_f32 %0, %1, %2" : "=v"(r) : "v"(a), "v"(b));
    return r;   // low16 = bf16(a), high16 = bf16(b)
}

#define GLOAD_LDS16(g, l) __builtin_amdgcn_global_load_lds( \
    (const __attribute__((address_space(1))) void*)(g),     \
    (__attribute__((address_space(3))) void*)(l), 16, 0, 0)

struct us4 { unsigned short a, b, c, d; };

// ---------------- fused prep A: x->bf16, 4 weight transposes, rope table ----------------
// flat grid: [0,8192) x-convert | [8192,18432) transposes | [18432,18944) rope table

__global__ __launch_bounds__(256)
void prep_a(const float* __restrict__ x, const float* __restrict__ wq,
            const float* __restrict__ wk, const float* __restrict__ wv,
            const float* __restrict__ wo,
            unsigned short* __restrict__ xbf, unsigned short* __restrict__ wqkvT,
            unsigned short* __restrict__ woT,
            float* __restrict__ cosT, float* __restrict__ sinT) {
    __shared__ float tile[32][33];
    int blk = blockIdx.x;
    if (blk < 8192) {                               // x: f32 -> bf16, 4 elems/thread
        long i = ((long)blk * 256 + threadIdx.x) * 4;
        float4 f = *(const float4*)(x + i);
        us4 o; o.a = f2bf(f.x); o.b = f2bf(f.y); o.c = f2bf(f.z); o.d = f2bf(f.w);
        *(us4*)(xbf + i) = o;
        return;
    }
    blk -= 8192;
    if (blk < 10240) {                              // weight transposes
        const float* in; unsigned short* outp; int C, bx, by;
        if (blk < 4096)      { in = wq; outp = wqkvT;                         C = DM;  bx = blk & 63;          by = blk >> 6; }
        else if (blk < 5120) { int k = blk - 4096; in = wk; outp = wqkvT + (long)DM * DM;         C = 512; bx = k & 15; by = k >> 4; }
        else if (blk < 6144) { int k = blk - 5120; in = wv; outp = wqkvT + (long)(DM + 512) * DM; C = 512; bx = k & 15; by = k >> 4; }
        else                 { int k = blk - 6144; in = wo; outp = woT;                           C = DM;  bx = k & 63; by = k >> 6; }
        const int c0 = bx * 32, r0 = by * 32;
        const int tx = threadIdx.x & 31, ty = threadIdx.x >> 5;
#pragma unroll
        for (int i = 0; i < 4; ++i)
            tile[ty + i * 8][tx] = in[(long)(r0 + ty + i * 8) * C + c0 + tx];
        __syncthreads();
#pragma unroll
        for (int i = 0; i < 4; ++i)
            outp[(long)(c0 + ty + i * 8) * DM + r0 + tx] = f2bf(tile[tx][ty + i * 8]);
        return;
    }
    blk -= 10240;                                   // rope table (512 blocks)
    const int idx = blk * 256 + threadIdx.x;        // < 2048*64
    const int t = idx >> 6, d = idx & 63;
    const float inv = __expf(-(float)d * (9.210340371976184f / 64.0f)); // 10000^(-d/64)
    const float ang = (float)t * inv;
    cosT[idx] = cosf(ang);
    sinT[idx] = sinf(ang);
}

// ---------------- fused prep B: rope apply (q,k) + v transpose ----------------
// flat grid: [0,5120) rope | [5120,7168) v-transpose

__global__ __launch_bounds__(256)
void prep_b(unsigned short* __restrict__ qkv,
            const float* __restrict__ cosT, const float* __restrict__ sinT,
            unsigned short* __restrict__ vt) {
    __shared__ unsigned short stile[32][33];
    int blk = blockIdx.x;
    if (blk < 5120) {                               // RoPE, 4 d-values/thread
        const int idx = blk * 256 + threadIdx.x;    // 4096*20*16
        const int d4 = (idx & 15) * 4;
        const int hh = (idx >> 4) % 20;
        const int row = idx / (16 * 20);
        const int t = row & (T_SEQ - 1);
        const int col = (hh < N_Q) ? hh * HD + d4 : DM + (hh - N_Q) * HD + d4;
        unsigned short* p = qkv + (long)row * NQKV + col;
        us4v a = *(const us4v*)p;
        us4v b = *(const us4v*)(p + 64);
        float4 c = *(const float4*)&cosT[t * 64 + d4];
        float4 s = *(const float4*)&sinT[t * 64 + d4];
        const float sc = (hh < N_Q) ? QK_SCALE_L2E : 1.0f;
        us4v o1, o2;
        const float cc[4] = { c.x, c.y, c.z, c.w }, ss[4] = { s.x, s.y, s.z, s.w };
#pragma unroll
        for (int i = 0; i < 4; ++i) {
            const float av = bf2f(a[i]), bv = bf2f(b[i]);
            o1[i] = f2bf((av * cc[i] - bv * ss[i]) * sc);
            o2[i] = f2bf((bv * cc[i] + av * ss[i]) * sc);
        }
        *(us4v*)p        = o1;
        *(us4v*)(p + 64) = o2;
        return;
    }
    blk -= 5120;                                    // v transpose (2048 blocks)
    const int bh = blk >> 8;                        // b*4 + hkv
    const int d0 = ((blk >> 6) & 3) * 32;
    const int t0 = (blk & 63) * 32;
    const int tx = threadIdx.x & 31, ty = threadIdx.x >> 5;
    const long inbase = (long)(bh >> 2) * T_SEQ;
    const int coff = DM + N_KV * HD + (bh & 3) * HD;   // 2560 + hkv*128
#pragma unroll
    for (int i = 0; i < 4; ++i)
        stile[ty + i * 8][tx] = qkv[(inbase + t0 + ty + i * 8) * NQKV + coff + d0 + tx];
    __syncthreads();
#pragma unroll
    for (int i = 0; i < 4; ++i)
        vt[((long)bh * HD + d0 + ty + i * 8) * T_SEQ + t0 + tx] = stile[tx][ty + i * 8];
}

// ---------------- GEMM: C[M][ldc] = A[M][K] * Bt[N][K]^T ----------------
// m97 structure, 32x32x16 MFMA (half the MFMA instructions of 16x16x32 at
// +15% pipe rate). LDS swizzle deepened to (row ^ row>>3)&7 because all four
// hi-groups now read the same 32 rows (plain row&7 would 4-way conflict).
// A/B k-map assumption cancels by sigma-invariance (same map both operands).
// C/D map (HW-verified m74/m101): col=lane&31, row=(r&3)+8*(r>>2)+4*(lane>>5).

template<int OUT_BF16>
__global__ __launch_bounds__(256)
void gemm_bt(const unsigned short* __restrict__ A,
             const unsigned short* __restrict__ Bt,
             void* __restrict__ Cvoid, int K, int ldc) {
    __shared__ __align__(16) unsigned short sA[128 * 64];
    __shared__ __align__(16) unsigned short sB[128 * 64];
    const int tid = threadIdx.x;
    const int lane = tid & 63;
    const int wid = tid >> 6;
    const int wr = (wid >> 1) * 64, wc = (wid & 1) * 64;
    const int l5 = lane >> 5, l31 = lane & 31;

    // XCD-aware bijective swizzle (nwg divisible by 8 in all launches)
    const int gx = gridDim.x;
    const int nwg = gx * gridDim.y;
    int flat = blockIdx.y * gx + blockIdx.x;
    flat = (flat & 7) * (nwg >> 3) + (flat >> 3);
    const long Arow0 = (long)(flat / gx) * 128;
    const long Brow0 = (long)(flat % gx) * 128;

    f32x16 acc[2][2] = {};

    for (int kt = 0; kt < K; kt += 64) {
        __syncthreads();
#pragma unroll
        for (int n = 0; n < 4; ++n) {
            const int linb = n * 256 + wid * 64;      // wave-uniform 16B-chunk base
            const int lin  = linb + lane;             // this lane's chunk
            const int row  = lin >> 3;                // 8 chunks per 64-elem row
            const int sw   = (row ^ (row >> 3)) & 7;
            const int sc   = (lin & 7) ^ sw;          // pre-swizzled global source
            const unsigned short* gA = A  + (Arow0 + row) * K + kt + sc * 8;
            const unsigned short* gB = Bt + (Brow0 + row) * K + kt + sc * 8;
            GLOAD_LDS16(gA, &sA[linb * 8]);
            GLOAD_LDS16(gB, &sB[linb * 8]);
        }
        __syncthreads();
#pragma unroll
        for (int kc = 0; kc < 4; ++kc) {
            bf16x8 av[2], bv[2];
#pragma unroll
            for (int t = 0; t < 2; ++t) {
                const int rowa = wr + t * 32 + l31;
                const int ca = (kc * 2 + l5) ^ ((rowa ^ (rowa >> 3)) & 7);
                av[t] = *(const bf16x8*)&sA[rowa * 64 + ca * 8];
                const int rowb = wc + t * 32 + l31;
                const int cb = (kc * 2 + l5) ^ ((rowb ^ (rowb >> 3)) & 7);
                bv[t] = *(const bf16x8*)&sB[rowb * 64 + cb * 8];
            }
#pragma unroll
            for (int ti = 0; ti < 2; ++ti)
#pragma unroll
                for (int tj = 0; tj < 2; ++tj)
                    acc[ti][tj] = __builtin_amdgcn_mfma_f32_32x32x16_bf16(av[ti], bv[tj], acc[ti][tj], 0, 0, 0);
        }
    }

#pragma unroll
    for (int ti = 0; ti < 2; ++ti)
#pragma unroll
        for (int tj = 0; tj < 2; ++tj)
#pragma unroll
            for (int r = 0; r < 16; ++r) {
                const long row = Arow0 + wr + ti * 32 + (r & 3) + 8 * (r >> 2) + 4 * l5;
                const long col = Brow0 + wc + tj * 32 + l31;
                if (OUT_BF16)
                    ((unsigned short*)Cvoid)[row * ldc + col] = f2bf(acc[ti][tj][r]);
                else
                    ((float*)Cvoid)[row * ldc + col] = acc[ti][tj][r];
            }
}

// ---------------- flash attention, sliding window ----------------
// grid (T/64, N_KV, B), 512 threads = 8 waves.
// wave w: q-head = hkv*4 + (w&3), q-rows = qt*64 + (w>>2)*32 + [0,32).
// All 8 waves share the staged K/V tiles (4 q-heads x 2 q-halves).
// Swapped QK^T (S^T in regs, lane-local softmax), exp2 domain, defer-max,
// double-buffered K/V staging, wave-uniform mask hoisting, LDS P roundtrip.

__global__ __launch_bounds__(512, 2)
void attn_kernel(const unsigned short* __restrict__ qkv,
                 const unsigned short* __restrict__ vt,
                 unsigned short* __restrict__ aout) {
    const int qt = blockIdx.x, hkv = blockIdx.y, b = blockIdx.z;
    const int tid = threadIdx.x, lane = tid & 63, w = tid >> 6;
    const int qh = hkv * 4 + (w & 3);          // q-head for this wave
    const int qsub = w >> 2;                   // 0 or 1: which 32-row half
    const int q0w = qt * 64 + qsub * 32;       // wave's first q-row
    const int lo = lane & 15, hi = lane >> 4;

    __shared__ __align__(16) unsigned short sK[2][64 * 128];   // [key][d], chunk-swizzled
    __shared__ __align__(16) unsigned short sV[2][128 * 64];   // [d][key], chunk-swizzled
    __shared__ __align__(16) unsigned short plds[8][32 * 64];  // per-wave P, [q][key^swz]
    unsigned short* pl = plds[w];

    // Q fragments: 2 q-frags x 4 k-chunks
    bf16x8 qf2[2][4];
#pragma unroll
    for (int f = 0; f < 2; ++f) {
        const unsigned short* qp = qkv + (long)(b * T_SEQ + q0w + f * 16 + lo) * NQKV + qh * HD + hi * 8;
#pragma unroll
        for (int s = 0; s < 4; ++s) qf2[f][s] = *(const bf16x8*)(qp + s * 32);
    }

    f32x4 of[8][2] = {};
    float m_r[2] = { -1e30f, -1e30f };   // running max for q = q0w + f*16 + lo
    float s_r[2] = { 0.f, 0.f };

    int kstart = qt * 64 - (WIN - 1);
    if (kstart < 0) kstart = 0;
    kstart &= ~63;
    const int kend = qt * 64 + 63;

    const unsigned short* kbase = qkv + (long)b * T_SEQ * NQKV + DM + hkv * HD;
    const unsigned short* vbase = vt + (long)(b * N_KV + hkv) * HD * T_SEQ;

    // staging offsets (pre-swizzled global source, linear LDS dest); 512 thr x 2 chunks each
    int kr[2], kc[2], vr[2], vc[2];
#pragma unroll
    for (int u = 0; u < 2; ++u) {
        const int c = u * 512 + tid;
        kr[u] = c >> 4;  kc[u] = (c & 15) ^ (kr[u] & 7);   // sK: 16 chunks/row
        vr[u] = c >> 3;  vc[u] = (c & 7) ^ (vr[u] & 7);    // sV: 8 chunks/row
    }

#define STAGE(bf, kt_) do {                                                              \
    _Pragma("unroll")                                                                    \
    for (int u = 0; u < 2; ++u) {                                                        \
        const int dbase = (u * 512 + w * 64) * 8;                                        \
        GLOAD_LDS16(kbase + (long)((kt_) + kr[u]) * NQKV + kc[u] * 8, &sK[bf][dbase]);   \
        GLOAD_LDS16(vbase + (long)vr[u] * T_SEQ + (kt_) + vc[u] * 8, &sV[bf][dbase]);    \
    } } while (0)

    STAGE(0, kstart);
    asm volatile("s_waitcnt vmcnt(0)" ::: "memory");
    __syncthreads();

    int buf = 0;
    for (int kt = kstart; kt <= kend; kt += 64) {
        if (kt + 64 <= kend) STAGE(buf ^ 1, kt + 64);

        // ---- swapped QK^T: sf[n][f] = S^T[key = kt+n*16+hi*4+r][q = q0w+f*16+lo] ----
        f32x4 sf[4][2] = {};
        __builtin_amdgcn_s_setprio(1);
#pragma unroll
        for (int n = 0; n < 4; ++n) {
            const int row = n * 16 + lo;
#pragma unroll
            for (int s = 0; s < 4; ++s) {
                const int c = (s * 4 + hi) ^ (row & 7);
                bf16x8 kf = *(const bf16x8*)&sK[buf][row * 128 + c * 8];
                sf[n][0] = __builtin_amdgcn_mfma_f32_16x16x32_bf16(kf, qf2[0][s], sf[n][0], 0, 0, 0);
                sf[n][1] = __builtin_amdgcn_mfma_f32_16x16x32_bf16(kf, qf2[1][s], sf[n][1], 0, 0, 0);
            }
        }
        __builtin_amdgcn_s_setprio(0);

        // ---- wave-uniform mask hoisting: interior tiles skip all masking ----
        // causal needed iff max-key (kt+63) > min-q (q0w); window needed iff
        // max-d = (q0w+31) - kt >= WIN. Interior => predicate false elementwise.
        const bool nomask = ((kt + 63) <= q0w) && ((q0w + 31 - kt) < WIN);

        // ---- lane-local online softmax, 2 q-frags ----
        float pv[2][4][4];
        float mx[2] = { -1e30f, -1e30f };
        if (nomask) {
#pragma unroll
            for (int f = 0; f < 2; ++f)
#pragma unroll
                for (int n = 0; n < 4; ++n)
#pragma unroll
                    for (int r = 0; r < 4; ++r) {
                        pv[f][n][r] = sf[n][f][r];
                        mx[f] = fmaxf(mx[f], pv[f][n][r]);
                    }
        } else {
#pragma unroll
            for (int f = 0; f < 2; ++f) {
                const int q = q0w + f * 16 + lo;
#pragma unroll
                for (int n = 0; n < 4; ++n)
#pragma unroll
                    for (int r = 0; r < 4; ++r) {
                        const int d = q - (kt + n * 16 + hi * 4 + r);
                        pv[f][n][r] = (d >= 0 && d < WIN) ? sf[n][f][r] : -1e30f;
                        mx[f] = fmaxf(mx[f], pv[f][n][r]);
                    }
            }
        }
#pragma unroll
        for (int f = 0; f < 2; ++f) {
            mx[f] = fmaxf(mx[f], __shfl_xor(mx[f], 16));
            mx[f] = fmaxf(mx[f], __shfl_xor(mx[f], 32));
        }

        const bool ok = (mx[0] <= m_r[0] + 8.0f) && (mx[1] <= m_r[1] + 8.0f);
        if (!__all(ok)) {                          // defer-max: rescale rarely
#pragma unroll
            for (int f = 0; f < 2; ++f) {
                const float mnew = fmaxf(m_r[f], mx[f]);
                const float resc = exp2f(m_r[f] - mnew);
                s_r[f] *= resc;
                m_r[f] = mnew;
                float r4[4];
#pragma unroll
                for (int r = 0; r < 4; ++r) r4[r] = __shfl(resc, hi * 4 + r);
#pragma unroll
                for (int j = 0; j < 8; ++j) {
                    of[j][f][0] *= r4[0]; of[j][f][1] *= r4[1];
                    of[j][f][2] *= r4[2]; of[j][f][3] *= r4[3];
                }
            }
        }

#pragma unroll
        for (int f = 0; f < 2; ++f) {
            float psum = 0.f;
#pragma unroll
            for (int n = 0; n < 4; ++n)
#pragma unroll
                for (int r = 0; r < 4; ++r) {
                    pv[f][n][r] = exp2f(pv[f][n][r] - m_r[f]);
                    psum += pv[f][n][r];
                }
            psum += __shfl_xor(psum, 16);
            psum += __shfl_xor(psum, 32);
            s_r[f] += psum;
        }

        // ---- pack P -> per-wave swizzled LDS (u32 writes, cvt_pk) ----
        const int swz = (lo & 7) << 3;
#pragma unroll
        for (int f = 0; f < 2; ++f) {
            const int rowq = f * 16 + lo;
#pragma unroll
            for (int n = 0; n < 4; ++n) {
                const int k0 = n * 16 + hi * 4;
                *(unsigned*)&pl[rowq * 64 + (k0 ^ swz)]       = cvt_pk_bf16(pv[f][n][0], pv[f][n][1]);
                *(unsigned*)&pl[rowq * 64 + ((k0 + 2) ^ swz)] = cvt_pk_bf16(pv[f][n][2], pv[f][n][3]);
            }
        }
        asm volatile("s_waitcnt lgkmcnt(0)" ::: "memory");
        __builtin_amdgcn_sched_barrier(0);
        bf16x8 pa2[2][2];
#pragma unroll
        for (int f = 0; f < 2; ++f)
#pragma unroll
            for (int ks = 0; ks < 2; ++ks) {
                const int c = (ks * 4 + hi) ^ (lo & 7);
                pa2[f][ks] = *(const bf16x8*)&pl[(f * 16 + lo) * 64 + c * 8];
            }

        // ---- PV: of[j][f] += P[q-frag f] . V[d=j*16+lo] ----
        __builtin_amdgcn_s_setprio(1);
#pragma unroll
        for (int j = 0; j < 8; ++j) {
            const int row = j * 16 + lo;
#pragma unroll
            for (int ks = 0; ks < 2; ++ks) {
                const int c = (ks * 4 + hi) ^ (row & 7);
                bf16x8 vf = *(const bf16x8*)&sV[buf][row * 64 + c * 8];
                of[j][0] = __builtin_amdgcn_mfma_f32_16x16x32_bf16(pa2[0][ks], vf, of[j][0], 0, 0, 0);
                of[j][1] = __builtin_amdgcn_mfma_f32_16x16x32_bf16(pa2[1][ks], vf, of[j][1], 0, 0, 0);
            }
        }
        __builtin_amdgcn_s_setprio(0);

        asm volatile("s_waitcnt vmcnt(0)" ::: "memory");
        __syncthreads();
        buf ^= 1;
    }
#undef STAGE

#pragma unroll
    for (int f = 0; f < 2; ++f) {
        float s4[4];
#pragma unroll
        for (int r = 0; r < 4; ++r) s4[r] = __shfl(s_r[f], hi * 4 + r);
#pragma unroll
        for (int r = 0; r < 4; ++r) {
            const int qrow = q0w + f * 16 + hi * 4 + r;
            const float inv = 1.0f / s4[r];
            unsigned short* op = aout + (long)(b * T_SEQ + qrow) * DM + qh * HD + lo;
#pragma unroll
            for (int j = 0; j < 8; ++j) op[j * 16] = f2bf(of[j][f][r] * inv);
        }
    }
}

// ---------------- launch ----------------

extern "C" void kernel_launch(void* const* d_in, const int* in_sizes, int n_in,
                              void* d_out, int out_size, void* d_ws, size_t ws_size,
                              hipStream_t stream) {
    (void)in_sizes; (void)n_in; (void)out_size; (void)ws_size;
    const float* x  = (const float*)d_in[0];
    const float* wq = (const float*)d_in[1];
    const float* wk = (const float*)d_in[2];
    const float* wv = (const float*)d_in[3];
    const float* wo = (const float*)d_in[4];
    float* out = (float*)d_out;
    char* ws = (char*)d_ws;

    unsigned short* xbf   = (unsigned short*)(ws);                // 16,777,216 B
    unsigned short* wqkvT = (unsigned short*)(ws + 16777216);     // 12,582,912 B
    unsigned short* woT   = (unsigned short*)(ws + 29360128);     //  8,388,608 B
    unsigned short* qkv   = (unsigned short*)(ws + 37748736);     // 25,165,824 B
    unsigned short* vt    = (unsigned short*)(ws + 62914560);     //  4,194,304 B
    unsigned short* aout  = (unsigned short*)(ws + 67108864);     // 16,777,216 B
    float* cosT = (float*)(ws + 83886080);                        //    524,288 B
    float* sinT = (float*)(ws + 84410368);                        //    524,288 B

    prep_a<<<dim3(18944), dim3(256), 0, stream>>>(x, wq, wk, wv, wo, xbf, wqkvT, woT, cosT, sinT);
    gemm_bt<1><<<dim3(NQKV / 128, 32), dim3(256), 0, stream>>>(xbf, wqkvT, qkv, DM, NQKV);
    prep_b<<<dim3(7168), dim3(256), 0, stream>>>(qkv, cosT, sinT, vt);
    attn_kernel<<<dim3(T_SEQ / 64, 4, 2), dim3(512), 0, stream>>>(qkv, vt, aout);
    gemm_bt<0><<<dim3(DM / 128, 32), dim3(256), 0, stream>>>(aout, woT, out, DM, DM);
}